// Round 7
// baseline (633.560 us; speedup 1.0000x reference)
//
#include <hip/hip_runtime.h>
#include <hip/hip_bf16.h>
#include <math.h>

// ---------------------------------------------------------------------------
// GMVAE fused pipeline. Round 17 (on top of r16, 618.7us):
//  - attn_fused: serial per-kc P-write phase (1 wave writing, 3 waiting)
//    replaced by a parallel upfront P-slab write: each wave writes its own
//    64-col P slice into per-kc slabs [64][32] (same layout as old Psh ->
//    identical PV read pattern). Same split_store values, same ascending-kc
//    PV accumulation -> bit-exact. LDS 43 -> 122 KB (1 block/CU anyway).
//  - em_step: z-tile staging vectorized (16 coalesced float4 loads + b128
//    LDS writes instead of 64 scalar pairs). Pure copy reorg, bit-exact.
// Everything else unchanged from r16 (verified, absmax 0.0).
// ---------------------------------------------------------------------------

#define BATCH 16
#define SEQ 256
#define DIM 512
#define NH 4
#define DH 128
#define LD 64
#define KC 20
#define MC 10
#define NPTS 2560
#define BS_TOT 4096
#define NROWS 40960
#define LOG_NORM (-0.9189385332046727f)

typedef __attribute__((ext_vector_type(8))) short bf16x8;
typedef __attribute__((ext_vector_type(4))) float f32x4;
typedef __hip_bfloat16 bf;

__device__ inline float warpReduceSum(float v) {
    for (int o = 32; o > 0; o >>= 1) v += __shfl_down(v, o);
    return v;
}

__device__ inline void async_copy16(const bf* g, bf* l) {
    __builtin_amdgcn_global_load_lds(
        (const __attribute__((address_space(1))) unsigned int*)g,
        (__attribute__((address_space(3))) unsigned int*)l, 16, 0, 0);
}

__device__ inline void split_store(float x, bf* ph, bf* pl, long idx) {
    const bf h = __float2bfloat16(x);
    ph[idx] = h;
    pl[idx] = __float2bfloat16(x - __bfloat162float(h));
}

// ---------------------------------------------------------------------------
// Split-bf16 MFMA GEMM, 64x128 tile, BK=32 staged, K-unrolled x2 (two buffer
// sets, one barrier pair per 64-K). 4 waves x (4x2 MFMAs x 3 split groups)
// per 32-K tile. K must be a multiple of 64 (512 here).
// MODE: 0=QKV(fused q/k/vT out) 3=OPROJ(bias,relu,+resid) 4=STATS(fp32+bias)
// ---------------------------------------------------------------------------
template<int MODE>
__global__ __launch_bounds__(256, 3)
void gemm3t(const bf* __restrict__ Ah, const bf* __restrict__ Al,
            const bf* __restrict__ Bh, const bf* __restrict__ Bl,
            int K, int lda, int ldb,
            const float* __restrict__ b0, const float* __restrict__ b1v,
            const float* __restrict__ b2v,
            float* __restrict__ outF,
            bf* __restrict__ P1h, bf* __restrict__ P1l,
            bf* __restrict__ P2h, bf* __restrict__ P2l,
            bf* __restrict__ P3h, bf* __restrict__ P3l,
            const bf* __restrict__ Rh, const bf* __restrict__ Rl)
{
    // two 24 KB buffer sets
    __shared__ __align__(16) char smem[49152];
    float* Xs = (float*)smem;        // epilogue overlay [64][68] = 17408 B

    const int t = threadIdx.x;
    const int m0 = blockIdx.y * 64, n0 = blockIdx.x * 128;
    const int w = t >> 6, lane = t & 63;
    const int wn = w * 32;
    const int fm = lane & 15, quad = lane >> 4, fk = quad * 8;
    const int srow = t >> 2, scol = (t & 3) * 8;

    f32x4 acc[4][2];
#pragma unroll
    for (int i = 0; i < 4; i++)
#pragma unroll
        for (int j = 0; j < 2; j++) acc[i][j] = (f32x4){0.f, 0.f, 0.f, 0.f};

    const int nk2 = K >> 6;
    for (int kk2 = 0; kk2 < nk2; kk2++) {
#pragma unroll
        for (int h = 0; h < 2; h++) {
            const int kk = kk2 * 2 + h;
            char* base = smem + h * 24576;
            bf* Ash = (bf*)base;
            bf* Asl = (bf*)(base + 4096);
            bf* Bsh = (bf*)(base + 8192);
            bf* Bsl = (bf*)(base + 16384);
            const long ao = (long)(m0 + srow) * lda + kk * 32 + scol;
            const long bo = (long)(n0 + srow) * ldb + kk * 32 + scol;
            async_copy16(Ah + ao, Ash + w * 512);
            async_copy16(Al + ao, Asl + w * 512);
            async_copy16(Bh + bo, Bsh + w * 512);
            async_copy16(Bh + bo + 64L * ldb, Bsh + 2048 + w * 512);
            async_copy16(Bl + bo, Bsl + w * 512);
            async_copy16(Bl + bo + 64L * ldb, Bsl + 2048 + w * 512);
        }
        __syncthreads();

#pragma unroll
        for (int h = 0; h < 2; h++) {
            char* base = smem + h * 24576;
            bf* Ash = (bf*)base;
            bf* Asl = (bf*)(base + 4096);
            bf* Bsh = (bf*)(base + 8192);
            bf* Bsl = (bf*)(base + 16384);
            bf16x8 afh[4], afl[4], bfh[2], bfl[2];
#pragma unroll
            for (int mi = 0; mi < 4; mi++) {
                afh[mi] = *(const bf16x8*)&Ash[(mi * 16 + fm) * 32 + fk];
                afl[mi] = *(const bf16x8*)&Asl[(mi * 16 + fm) * 32 + fk];
            }
#pragma unroll
            for (int ni = 0; ni < 2; ni++) {
                bfh[ni] = *(const bf16x8*)&Bsh[(wn + ni * 16 + fm) * 32 + fk];
                bfl[ni] = *(const bf16x8*)&Bsl[(wn + ni * 16 + fm) * 32 + fk];
            }
#pragma unroll
            for (int mi = 0; mi < 4; mi++)
#pragma unroll
                for (int ni = 0; ni < 2; ni++) {
                    acc[mi][ni] = __builtin_amdgcn_mfma_f32_16x16x32_bf16(
                        afh[mi], bfh[ni], acc[mi][ni], 0, 0, 0);
                    acc[mi][ni] = __builtin_amdgcn_mfma_f32_16x16x32_bf16(
                        afh[mi], bfl[ni], acc[mi][ni], 0, 0, 0);
                    acc[mi][ni] = __builtin_amdgcn_mfma_f32_16x16x32_bf16(
                        afl[mi], bfh[ni], acc[mi][ni], 0, 0, 0);
                }
        }
        __syncthreads();
    }

    // ---- epilogue: two 64-col half-passes through LDS fp32 staging ----
    const int rl = t >> 2;
    const int cc4 = (t & 3) * 16;

    for (int p = 0; p < 2; p++) {
        if ((w >> 1) == p) {
            const int cb = wn - p * 64;
#pragma unroll
            for (int mi = 0; mi < 4; mi++)
#pragma unroll
                for (int ni = 0; ni < 2; ni++) {
                    const int c = cb + ni * 16 + fm;
#pragma unroll
                    for (int r = 0; r < 4; r++)
                        Xs[(mi * 16 + quad * 4 + r) * 68 + c] = acc[mi][ni][r];
                }
        }
        __syncthreads();

        if (MODE == 0 && n0 >= 1024) {
            const int hh = (n0 >> 7) & 3;
            const int dd = p * 64 + rl;
            const int bb = m0 >> 8;
            const int sb = (m0 & 255) + cc4;
            const float bias = b2v[hh * 128 + dd];
            const long ob = (((long)(bb * NH + hh) * DH + dd) << 8) + sb;
#pragma unroll
            for (int j = 0; j < 2; j++) {
                bf16x8 vh, vl;
#pragma unroll
                for (int i = 0; i < 8; i++) {
                    const float x = Xs[(cc4 + j * 8 + i) * 68 + rl] + bias;
                    const bf h = __float2bfloat16(x);
                    vh[i] = *(const short*)&h;
                    const bf l = __float2bfloat16(x - __bfloat162float(h));
                    vl[i] = *(const short*)&l;
                }
                *(bf16x8*)&P3h[ob + j * 8] = vh;
                *(bf16x8*)&P3l[ob + j * 8] = vl;
            }
        } else {
            float xv[16];
#pragma unroll
            for (int i = 0; i < 4; i++)
                *(float4*)&xv[i * 4] = *(const float4*)&Xs[rl * 68 + cc4 + i * 4];

            if (MODE == 0) {
                const int which = n0 >> 9;
                const int colq = (n0 & 511) + p * 64 + cc4;
                const float* bias = which ? b1v : b0;
                bf* Ph = which ? P2h : P1h;
                bf* Pl = which ? P2l : P1l;
                const long ob = (long)(m0 + rl) * 512 + colq;
#pragma unroll
                for (int j = 0; j < 2; j++) {
                    bf16x8 vh, vl;
#pragma unroll
                    for (int i = 0; i < 8; i++) {
                        const float x = xv[j * 8 + i] + bias[colq + j * 8 + i];
                        const bf h = __float2bfloat16(x); vh[i] = *(const short*)&h;
                        const bf l = __float2bfloat16(x - __bfloat162float(h));
                        vl[i] = *(const short*)&l;
                    }
                    *(bf16x8*)&Ph[ob + j * 8] = vh;
                    *(bf16x8*)&Pl[ob + j * 8] = vl;
                }
            } else if (MODE == 3) {
                const int colg = n0 + p * 64 + cc4;
                const long ob = (long)(m0 + rl) * 512 + colg;
#pragma unroll
                for (int j = 0; j < 2; j++) {
                    const bf16x8 rh = *(const bf16x8*)&Rh[ob + j * 8];
                    const bf16x8 rv = *(const bf16x8*)&Rl[ob + j * 8];
                    bf16x8 vh, vl;
#pragma unroll
                    for (int i = 0; i < 8; i++) {
                        short sh = rh[i], sl = rv[i];
                        float x = fmaxf(xv[j * 8 + i] + b0[colg + j * 8 + i], 0.f)
                                + __bfloat162float(*(const bf*)&sh)
                                + __bfloat162float(*(const bf*)&sl);
                        const bf h = __float2bfloat16(x); vh[i] = *(const short*)&h;
                        const bf l = __float2bfloat16(x - __bfloat162float(h));
                        vl[i] = *(const short*)&l;
                    }
                    *(bf16x8*)&P1h[ob + j * 8] = vh;
                    *(bf16x8*)&P1l[ob + j * 8] = vl;
                }
            } else {
                const int colg = p * 64 + cc4;
                const long ob = (long)(m0 + rl) * 128 + colg;
#pragma unroll
                for (int i = 0; i < 4; i++) {
                    float4 v = *(float4*)&xv[i * 4];
                    v.x += b0[colg + i * 4 + 0];
                    v.y += b0[colg + i * 4 + 1];
                    v.z += b0[colg + i * 4 + 2];
                    v.w += b0[colg + i * 4 + 3];
                    *(float4*)&outF[ob + i * 4] = v;
                }
            }
        }
        __syncthreads();
    }
}

// ---------------------------------------------------------------------------
// Fused attention. r17: parallel upfront P-slab write (slab kc <-> wave
// kc>>1, half kc&1 — same data the old serial phase wrote at iteration kc,
// same [64][32] slab layout, same PV read pattern and kc-ascending MFMA
// order -> bit-exact). Serial 1-wave-writes-3-wait phase removed.
// ---------------------------------------------------------------------------
__global__ __launch_bounds__(256)
void attn_fused(const bf* __restrict__ qh, const bf* __restrict__ ql,
                const bf* __restrict__ kh, const bf* __restrict__ kl,
                const bf* __restrict__ vTh, const bf* __restrict__ vTl,
                bf* __restrict__ oh, bf* __restrict__ ol)
{
    __shared__ __align__(16) char smem[124928];
    bf* Qsh = (bf*)smem;            bf* Qsl = (bf*)(smem + 4096);
    bf* Ksh = (bf*)(smem + 8192);   bf* Ksl = (bf*)(smem + 24576);
    float (*red)[4]  = (float(*)[4])(smem + 40960);
    float (*red2)[4] = (float(*)[4])(smem + 41984);
    bf* PhB = (bf*)(smem + 43008);   // 8 slabs x [64][32] hi  (32 KB)
    bf* PlB = (bf*)(smem + 75776);   // 8 slabs x [64][32] lo  (32 KB)
    bf* Vsh = (bf*)(smem + 108544);
    bf* Vsl = (bf*)(smem + 116736);

    const int t = threadIdx.x;
    const int z = blockIdx.y;
    const int m0 = blockIdx.x * 64;
    const int bb = z >> 2, hh = z & 3;
    const long hOff = (long)bb * 131072 + (long)hh * 128;
    const long vOff = (long)z * 32768;

    const int w = t >> 6, lane = t & 63;
    const int fm = lane & 15;
    const int quad = lane >> 4;
    const int fk = quad * 8;
    const int srow = t >> 2, scol = (t & 3) * 8;

    f32x4 acc[4][4];
#pragma unroll
    for (int i = 0; i < 4; i++)
#pragma unroll
        for (int j = 0; j < 4; j++) acc[i][j] = (f32x4){0.f, 0.f, 0.f, 0.f};

    for (int kk = 0; kk < 4; kk++) {
        const long ao = hOff + (long)(m0 + srow) * 512 + kk * 32 + scol;
        const long bo = hOff + (long)srow * 512 + kk * 32 + scol;
        async_copy16(qh + ao, Qsh + w * 512);
        async_copy16(ql + ao, Qsl + w * 512);
#pragma unroll
        for (int j = 0; j < 4; j++) {
            async_copy16(kh + bo + (long)j * 64 * 512, Ksh + w * 512 + j * 2048);
            async_copy16(kl + bo + (long)j * 64 * 512, Ksl + w * 512 + j * 2048);
        }
        __syncthreads();

        bf16x8 afh[4], afl[4];
#pragma unroll
        for (int mi = 0; mi < 4; mi++) {
            afh[mi] = *(const bf16x8*)&Qsh[(mi * 16 + fm) * 32 + fk];
            afl[mi] = *(const bf16x8*)&Qsl[(mi * 16 + fm) * 32 + fk];
        }
#pragma unroll
        for (int ni = 0; ni < 4; ni++) {
            const bf16x8 bh = *(const bf16x8*)&Ksh[(w * 64 + ni * 16 + fm) * 32 + fk];
            const bf16x8 bl = *(const bf16x8*)&Ksl[(w * 64 + ni * 16 + fm) * 32 + fk];
#pragma unroll
            for (int mi = 0; mi < 4; mi++) {
                acc[mi][ni] = __builtin_amdgcn_mfma_f32_16x16x32_bf16(
                    afh[mi], bh, acc[mi][ni], 0, 0, 0);
                acc[mi][ni] = __builtin_amdgcn_mfma_f32_16x16x32_bf16(
                    afh[mi], bl, acc[mi][ni], 0, 0, 0);
                acc[mi][ni] = __builtin_amdgcn_mfma_f32_16x16x32_bf16(
                    afl[mi], bh, acc[mi][ni], 0, 0, 0);
            }
        }
        __syncthreads();
    }

    const float alpha = 0.044194173824159216f;
#pragma unroll
    for (int mi = 0; mi < 4; mi++)
#pragma unroll
        for (int r = 0; r < 4; r++) {
            float m = -1e30f;
#pragma unroll
            for (int ni = 0; ni < 4; ni++) m = fmaxf(m, acc[mi][ni][r]);
            for (int o = 8; o > 0; o >>= 1) m = fmaxf(m, __shfl_xor(m, o));
            if (fm == 0) red[mi * 16 + quad * 4 + r][w] = m;
        }
    __syncthreads();
    float invr[4][4];
#pragma unroll
    for (int mi = 0; mi < 4; mi++)
#pragma unroll
        for (int r = 0; r < 4; r++) {
            const int rowl = mi * 16 + quad * 4 + r;
            const float mx = fmaxf(fmaxf(red[rowl][0], red[rowl][1]),
                                   fmaxf(red[rowl][2], red[rowl][3]));
            float s = 0.f;
#pragma unroll
            for (int ni = 0; ni < 4; ni++) {
                const float e = __expf((acc[mi][ni][r] - mx) * alpha);
                acc[mi][ni][r] = e;
                s += e;
            }
            for (int o = 8; o > 0; o >>= 1) s += __shfl_xor(s, o);
            if (fm == 0) red2[rowl][w] = s;
        }
    __syncthreads();
#pragma unroll
    for (int mi = 0; mi < 4; mi++)
#pragma unroll
        for (int r = 0; r < 4; r++) {
            const int rowl = mi * 16 + quad * 4 + r;
            invr[mi][r] = 1.f / (red2[rowl][0] + red2[rowl][1] + red2[rowl][2] + red2[rowl][3]);
        }

    // ---- all waves write their full P slices upfront (slabs 2w, 2w+1) ----
#pragma unroll
    for (int half = 0; half < 2; half++) {
        bf* Ph = PhB + (2 * w + half) * 2048;
        bf* Pl = PlB + (2 * w + half) * 2048;
        const int nib = half * 2;
#pragma unroll
        for (int mi = 0; mi < 4; mi++)
#pragma unroll
            for (int r = 0; r < 4; r++) {
                const int row = mi * 16 + quad * 4 + r;
#pragma unroll
                for (int j = 0; j < 2; j++) {
                    const float p = acc[mi][nib + j][r] * invr[mi][r];
                    const int cc = j * 16 + fm;
                    const bf h = __float2bfloat16(p);
                    Ph[row * 32 + cc] = h;
                    Pl[row * 32 + cc] = __float2bfloat16(p - __bfloat162float(h));
                }
            }
    }

    f32x4 acc2[4][2];
#pragma unroll
    for (int i = 0; i < 4; i++)
#pragma unroll
        for (int j = 0; j < 2; j++) acc2[i][j] = (f32x4){0.f, 0.f, 0.f, 0.f};

    for (int kc = 0; kc < 8; kc++) {
        const long vo = vOff + (long)srow * 256 + kc * 32 + scol;
        async_copy16(vTh + vo, Vsh + w * 512);
        async_copy16(vTh + vo + 64L * 256, Vsh + w * 512 + 2048);
        async_copy16(vTl + vo, Vsl + w * 512);
        async_copy16(vTl + vo + 64L * 256, Vsl + w * 512 + 2048);
        __syncthreads();

        const bf* Psh_k = PhB + kc * 2048;
        const bf* Psl_k = PlB + kc * 2048;
        bf16x8 pfh[4], pfl[4];
#pragma unroll
        for (int mi = 0; mi < 4; mi++) {
            pfh[mi] = *(const bf16x8*)&Psh_k[(mi * 16 + fm) * 32 + fk];
            pfl[mi] = *(const bf16x8*)&Psl_k[(mi * 16 + fm) * 32 + fk];
        }
#pragma unroll
        for (int ni = 0; ni < 2; ni++) {
            const bf16x8 vh = *(const bf16x8*)&Vsh[(w * 32 + ni * 16 + fm) * 32 + fk];
            const bf16x8 vl = *(const bf16x8*)&Vsl[(w * 32 + ni * 16 + fm) * 32 + fk];
#pragma unroll
            for (int mi = 0; mi < 4; mi++) {
                acc2[mi][ni] = __builtin_amdgcn_mfma_f32_16x16x32_bf16(
                    pfh[mi], vh, acc2[mi][ni], 0, 0, 0);
                acc2[mi][ni] = __builtin_amdgcn_mfma_f32_16x16x32_bf16(
                    pfh[mi], vl, acc2[mi][ni], 0, 0, 0);
                acc2[mi][ni] = __builtin_amdgcn_mfma_f32_16x16x32_bf16(
                    pfl[mi], vh, acc2[mi][ni], 0, 0, 0);
            }
        }
        __syncthreads();
    }

#pragma unroll
    for (int ni = 0; ni < 2; ni++) {
        const int col = hh * 128 + w * 32 + ni * 16 + fm;
#pragma unroll
        for (int mi = 0; mi < 4; mi++)
#pragma unroll
            for (int r = 0; r < 4; r++) {
                const int row = mi * 16 + quad * 4 + r;
                const long idx = (long)(bb * 256 + m0 + row) * 512 + col;
                const float x = acc2[mi][ni][r]
                    + __bfloat162float(qh[idx]) + __bfloat162float(ql[idx]);
                split_store(x, oh, ol, idx);
            }
    }
}

// ---------------------------------------------------------------------------
// plain-bf16 decoder GEMM, single dispatch, XCD swizzle, K-unrolled x2.
// ---------------------------------------------------------------------------
template<bool SQLOSS>
__global__ __launch_bounds__(256, 4)
void gemm_mfma(const bf* __restrict__ A, const bf* __restrict__ BT,
               bf* __restrict__ C,
               const float* __restrict__ bias,
               const float* __restrict__ Href,
               float* __restrict__ lossAcc,
               int K, int N)
{
    // two 16 KB buffer sets (A+B each 8 KB)
    __shared__ __align__(16) char smem[32768];
    bf* Cs  = (bf*)smem;             // epilogue overlay [64][136] = 17408 B
    __shared__ float redS[4];

    const int t = threadIdx.x;
    const int flat = blockIdx.y * gridDim.x + blockIdx.x;
    const int lane8 = flat & 7;
    const int grp = flat >> 3;
    const int n_blk = grp % gridDim.x;
    const int m_blk = (grp / gridDim.x) * 8 + lane8;
    const int m0 = m_blk * 128, n0 = n_blk * 128;

    const int w = t >> 6, lane = t & 63;
    const int wm = (w >> 1) * 64, wn = (w & 1) * 64;
    const int fm = lane & 15;
    const int quad = lane >> 4;
    const int fk = quad * 8;
    const int srow = t >> 2, scol = (t & 3) * 8;

    f32x4 acc[4][4];
#pragma unroll
    for (int i = 0; i < 4; i++)
#pragma unroll
        for (int j = 0; j < 4; j++) acc[i][j] = (f32x4){0.f, 0.f, 0.f, 0.f};

    const int nk2 = K >> 6;
    for (int kt2 = 0; kt2 < nk2; kt2++) {
#pragma unroll
        for (int h = 0; h < 2; h++) {
            const int kt = kt2 * 2 + h;
            bf* Asg = (bf*)(smem + h * 16384);
            bf* Bsg = (bf*)(smem + h * 16384 + 8192);
            const bf* ga = A + (long)(m0 + srow) * K + kt * 32 + scol;
            const bf* gb = BT + (long)(n0 + srow) * K + kt * 32 + scol;
            async_copy16(ga, Asg + w * 512);
            async_copy16(ga + 64L * K, Asg + 2048 + w * 512);
            async_copy16(gb, Bsg + w * 512);
            async_copy16(gb + 64L * K, Bsg + 2048 + w * 512);
        }
        __syncthreads();

#pragma unroll
        for (int h = 0; h < 2; h++) {
            bf* Asg = (bf*)(smem + h * 16384);
            bf* Bsg = (bf*)(smem + h * 16384 + 8192);
            bf16x8 af[4], bfr[4];
#pragma unroll
            for (int mi = 0; mi < 4; mi++)
                af[mi] = *(const bf16x8*)&Asg[(wm + mi * 16 + fm) * 32 + fk];
#pragma unroll
            for (int ni = 0; ni < 4; ni++)
                bfr[ni] = *(const bf16x8*)&Bsg[(wn + ni * 16 + fm) * 32 + fk];
#pragma unroll
            for (int mi = 0; mi < 4; mi++)
#pragma unroll
                for (int ni = 0; ni < 4; ni++)
                    acc[mi][ni] = __builtin_amdgcn_mfma_f32_16x16x32_bf16(
                        af[mi], bfr[ni], acc[mi][ni], 0, 0, 0);
        }
        __syncthreads();
    }

    if (SQLOSS) {
        float lsum = 0.f;
#pragma unroll
        for (int ni = 0; ni < 4; ni++) {
            const int col = n0 + wn + ni * 16 + fm;
            const float b = bias[col];
#pragma unroll
            for (int mi = 0; mi < 4; mi++)
#pragma unroll
                for (int r = 0; r < 4; r++) {
                    const int row = m0 + wm + mi * 16 + quad * 4 + r;
                    const float x = fmaxf(acc[mi][ni][r] + b, 0.f);
                    const float d = x - Href[(long)(row / MC) * DIM + col];
                    lsum = fmaf(d, d, lsum);
                }
        }
        lsum = warpReduceSum(lsum);
        if (lane == 0) redS[w] = lsum;
        __syncthreads();
        if (t == 0) atomicAdd(lossAcc, redS[0] + redS[1] + redS[2] + redS[3]);
    } else {
        for (int hf = 0; hf < 2; hf++) {
            if ((w >> 1) == hf) {
#pragma unroll
                for (int ni = 0; ni < 4; ni++) {
                    const int c = wn + ni * 16 + fm;
                    const float bv = bias[n0 + c];
#pragma unroll
                    for (int mi = 0; mi < 4; mi++)
#pragma unroll
                        for (int r = 0; r < 4; r++) {
                            const float x = fmaxf(acc[mi][ni][r] + bv, 0.f);
                            Cs[(mi * 16 + quad * 4 + r) * 136 + c] = __float2bfloat16(x);
                        }
                }
            }
            __syncthreads();
            const int rl2 = t >> 2, cc2 = (t & 3) * 32;
            const long ob = (long)(m0 + hf * 64 + rl2) * N + n0 + cc2;
#pragma unroll
            for (int j = 0; j < 4; j++)
                *(bf16x8*)&C[ob + j * 8] = *(const bf16x8*)&Cs[rl2 * 136 + cc2 + j * 8];
            __syncthreads();
        }
    }
}

// ---------------------------------------------------------------------------
// conv_all (r16 verified): block-range dispatch, 64x64 LDS tile-transposes.
// ---------------------------------------------------------------------------
__global__ __launch_bounds__(256)
void conv_all(
    const float* __restrict__ H, bf* __restrict__ h0h, bf* __restrict__ h0l,
    const float* __restrict__ wq, const float* __restrict__ wk,
    const float* __restrict__ wv, const float* __restrict__ wo,
    bf* __restrict__ qkvTh0, bf* __restrict__ qkvTl0,
    bf* __restrict__ woTh0, bf* __restrict__ woTl0,
    bf* __restrict__ qkvTh1, bf* __restrict__ qkvTl1,
    bf* __restrict__ woTh1, bf* __restrict__ woTl1,
    const float* __restrict__ wz, bf* __restrict__ wzTh, bf* __restrict__ wzTl,
    const float* __restrict__ w1, bf* __restrict__ w1T,
    const float* __restrict__ w2, bf* __restrict__ w2T,
    const float* __restrict__ w3, bf* __restrict__ w3T,
    float* __restrict__ scal, float* __restrict__ msP, float* __restrict__ nkP)
{
    __shared__ float tS[64][65];
    const int b = blockIdx.x, t = threadIdx.x;

    if (b < 2048) {                  // ---- H split, float4 ----
        const long base = ((long)b << 10) + (t << 2);
        const float4 v = *(const float4*)&H[base];
        ushort4 uh, ul;
        {
            const bf h0 = __float2bfloat16(v.x);
            uh.x = *(const unsigned short*)&h0;
            const bf l0 = __float2bfloat16(v.x - __bfloat162float(h0));
            ul.x = *(const unsigned short*)&l0;
        }
        {
            const bf h0 = __float2bfloat16(v.y);
            uh.y = *(const unsigned short*)&h0;
            const bf l0 = __float2bfloat16(v.y - __bfloat162float(h0));
            ul.y = *(const unsigned short*)&l0;
        }
        {
            const bf h0 = __float2bfloat16(v.z);
            uh.z = *(const unsigned short*)&h0;
            const bf l0 = __float2bfloat16(v.z - __bfloat162float(h0));
            ul.z = *(const unsigned short*)&l0;
        }
        {
            const bf h0 = __float2bfloat16(v.w);
            uh.w = *(const unsigned short*)&h0;
            const bf l0 = __float2bfloat16(v.w - __bfloat162float(h0));
            ul.w = *(const unsigned short*)&l0;
        }
        *(ushort4*)&h0h[base] = uh;
        *(ushort4*)&h0l[base] = ul;
        return;
    }
    const int bb = b - 2048;

    if (bb >= 928) {
        if (bb < 1028) {             // ---- zero msP buffers 1..5 ----
            const long j = ((long)(bb - 928) << 10) + (t << 2);
            *(float4*)&msP[20480 + j] = (float4){0.f, 0.f, 0.f, 0.f};
        } else {                     // ---- zero nkP 1..5 + scal ----
            for (int i = t; i < 1600; i += 256) nkP[320 + i] = 0.f;
            if (t < 16) scal[t] = 0.f;
        }
        return;
    }

    // ---- tile-transpose sections ----
    const float* src; bf* dH; bf* dL = nullptr;
    int Ncols, ldT, k0, n0; long dofs = 0; bool split;

    if (bb < 512) {                  // MAB weights
        const int m = bb >> 6, tile = bb & 63;
        const int layer = m >> 2, seg = m & 3;
        k0 = (tile >> 3) * 64; n0 = (tile & 7) * 64;
        src = ((seg == 0) ? wq : (seg == 1) ? wk : (seg == 2) ? wv : wo)
              + (long)layer * 262144;
        Ncols = 512; ldT = 512; split = true;
        if (seg < 3) {
            dH = layer ? qkvTh1 : qkvTh0;
            dL = layer ? qkvTl1 : qkvTl0;
            dofs = (long)seg * 262144;
        } else {
            dH = layer ? woTh1 : woTh0;
            dL = layer ? woTl1 : woTl0;
        }
    } else if (bb < 528) {           // wz
        const int i = bb - 512;
        k0 = (i >> 1) * 64; n0 = (i & 1) * 64;
        src = wz; Ncols = 128; ldT = 512; split = true;
        dH = wzTh; dL = wzTl;
    } else if (bb < 544) {           // w1
        const int i = bb - 528;
        k0 = 0; n0 = i * 64;
        src = w1; Ncols = 1024; ldT = 64; split = false;
        dH = w1T;
    } else if (bb < 800) {           // w2
        const int i = bb - 544;
        k0 = (i >> 4) * 64; n0 = (i & 15) * 64;
        src = w2; Ncols = 1024; ldT = 1024; split = false;
        dH = w2T;
    } else {                         // w3
        const int i = bb - 800;
        k0 = (i >> 3) * 64; n0 = (i & 7) * 64;
        src = w3; Ncols = 512; ldT = 1024; split = false;
        dH = w3T;
    }

    // load 64x64 fp32 tile coalesced
    {
        const int r = t >> 2, cq = (t & 3) * 16;
#pragma unroll
        for (int i = 0; i < 4; i++) {
            const float4 v = *(const float4*)&src[(long)(k0 + r) * Ncols + n0 + cq + i * 4];
            tS[r][cq + i * 4 + 0] = v.x;
            tS[r][cq + i * 4 + 1] = v.y;
            tS[r][cq + i * 4 + 2] = v.z;
            tS[r][cq + i * 4 + 3] = v.w;
        }
    }
    __syncthreads();

    // write transposed, coalesced bf16x8
    {
        const int nn = t >> 2, kq = (t & 3) * 16;
        const long ob = dofs + (long)(n0 + nn) * ldT + k0 + kq;
#pragma unroll
        for (int j2 = 0; j2 < 2; j2++) {
            bf16x8 vh, vl;
#pragma unroll
            for (int j = 0; j < 8; j++) {
                const float x = tS[kq + j2 * 8 + j][nn];
                const bf h = __float2bfloat16(x);
                vh[j] = *(const short*)&h;
                const bf l = __float2bfloat16(x - __bfloat162float(h));
                vl[j] = *(const short*)&l;
            }
            *(bf16x8*)&dH[ob + j2 * 8] = vh;
            if (split) *(bf16x8*)&dL[ob + j2 * 8] = vl;
        }
    }
}

// ---------------------------------------------------------------------------
__global__ __launch_bounds__(256)
void zgen(const float* __restrict__ stats, const float* __restrict__ eps,
          float* __restrict__ z, bf* __restrict__ z16)
{
    const int idx = blockIdx.x * 256 + threadIdx.x;
    const int bs = idx / 160;
    const int r = idx % 160;
    const int l4 = r % 16;
    const float4 e = ((const float4*)eps)[idx];
    const float4 mn = ((const float4*)stats)[bs * 32 + l4];
    const float4 lv = ((const float4*)stats)[bs * 32 + 16 + l4];
    float4 zz;
    zz.x = fmaf(e.x, expf(0.5f * lv.x), mn.x);
    zz.y = fmaf(e.y, expf(0.5f * lv.y), mn.y);
    zz.z = fmaf(e.z, expf(0.5f * lv.z), mn.z);
    zz.w = fmaf(e.w, expf(0.5f * lv.w), mn.w);
    ((float4*)z)[idx] = zz;
    bf* zp = z16 + (long)idx * 4;
    zp[0] = __float2bfloat16(zz.x);
    zp[1] = __float2bfloat16(zz.y);
    zp[2] = __float2bfloat16(zz.z);
    zp[3] = __float2bfloat16(zz.w);
}

// ---------------------------------------------------------------------------
// EM step (r15 verified + r17 vectorized staging): zbS LDS z-tile (float4
// coalesced copy, bit-exact), muS[KC][68] float4, FIRST folds init.
// ---------------------------------------------------------------------------
template<bool FIRST>
__global__ __launch_bounds__(256)
void em_step(const float* __restrict__ z, const int* __restrict__ init_idx,
             const float* __restrict__ msIn, const float* __restrict__ nkIn,
             float* __restrict__ msOut, float* __restrict__ nkOut)
{
    __shared__ float muS[KC][68];
    __shared__ float m2lp[KC];
    __shared__ float NkU[KC];
    __shared__ float postS[KC][256];
    __shared__ float NkS[KC];
    __shared__ float zbS[256][64];   // 64 KB tile stage

    const int tile = blockIdx.x, b = blockIdx.y, t = threadIdx.x;
    const int lane = t & 63, w = t >> 6;

    const float* zbg = &z[((long)b * NPTS + (long)tile * 256) * LD];

    // stage z tile -> LDS, float4 coalesced (bit-exact copy)
    {
        const int c4 = (t & 15) * 4;
        const int r0 = t >> 4;
#pragma unroll
        for (int p = 0; p < 16; p++) {
            const int r = r0 + p * 16;
            *(float4*)&zbS[r][c4] = *(const float4*)&zbg[(long)r * 64 + c4];
        }
    }

    if (t < KC) NkU[t] = FIRST ? 1.f : nkIn[b * KC + t];
    __syncthreads();
    if (FIRST) {
        for (int i = t; i < KC * LD; i += 256) {
            const int k = i >> 6, l = i & 63;
            muS[k][l] = z[((long)b * NPTS + init_idx[b * KC + k]) * LD + l];
        }
    } else {
        for (int i = t; i < KC * LD; i += 256)
            muS[i >> 6][i & 63] = msIn[b * KC * LD + i] / NkU[i >> 6];
    }
    __syncthreads();
    if (t < KC) {
        float s = 0.f;
        for (int l = 0; l < LD; l++) { const float m = muS[t][l]; s = fmaf(m, m, s); }
        float sn = 0.f;
        for (int k = 0; k < KC; k++) sn += NkU[k];
        m2lp[t] = -0.5f * s + logf(NkU[t] / sn);
    }
    __syncthreads();

    // ---- E-step (muS via aligned float4; same fmaf order) ----
    const float* zr = &zbg[(long)t * LD];
    float acc[KC];
#pragma unroll
    for (int k = 0; k < KC; k++) acc[k] = 0.f;
#pragma unroll
    for (int l4 = 0; l4 < 16; l4++) {
        const float4 zv = ((const float4*)zr)[l4];
#pragma unroll
        for (int k = 0; k < KC; k++) {
            const float4 mv = *(const float4*)&muS[k][l4 * 4];
            acc[k] = fmaf(zv.x, mv.x, acc[k]);
            acc[k] = fmaf(zv.y, mv.y, acc[k]);
            acc[k] = fmaf(zv.z, mv.z, acc[k]);
            acc[k] = fmaf(zv.w, mv.w, acc[k]);
        }
    }
    float mx = -1e30f;
    float llv[KC];
#pragma unroll
    for (int k = 0; k < KC; k++) { llv[k] = acc[k] + m2lp[k]; mx = fmaxf(mx, llv[k]); }
    float s = 0.f;
#pragma unroll
    for (int k = 0; k < KC; k++) { llv[k] = expf(llv[k] - mx); s += llv[k]; }
    const float inv = 1.f / s;
#pragma unroll
    for (int k = 0; k < KC; k++) postS[k][t] = llv[k] * inv;
    __syncthreads();

#pragma unroll
    for (int kk = 0; kk < 5; kk++) {
        const int k = w * 5 + kk;
        float p = postS[k][lane] + postS[k][lane + 64] + postS[k][lane + 128] + postS[k][lane + 192];
        p = warpReduceSum(p);
        if (lane == 0) NkS[k] = p;
    }
    __syncthreads();

    // ---- M-step: chains fed from zbS (same values, same n2 order) ----
#pragma unroll
    for (int j = 0; j < 5; j++) {
        const int o = t + j * 256;
        const int k = o >> 6, l = o & 63;
        float sacc = 0.f;
        for (int n2 = 0; n2 < 256; n2++)
            sacc = fmaf(postS[k][n2], zbS[n2][l], sacc);
        atomicAdd(&msOut[b * KC * LD + o], sacc);
    }
    if (t < KC) atomicAdd(&nkOut[b * KC + t], NkS[t]);
}

// ---------------------------------------------------------------------------
// KL kernel + folded finalize (r16 verified).
// ---------------------------------------------------------------------------
__global__ __launch_bounds__(256)
void kl_kernel(const float* __restrict__ z, const float* __restrict__ stats,
               const float* __restrict__ eps,
               const float* __restrict__ msIn, const float* __restrict__ nkIn,
               float* __restrict__ scal, float* __restrict__ out)
{
    __shared__ float muS[KC][68];
    __shared__ float m2lp[KC];
    __shared__ float NkU[KC];
    __shared__ float redS[4];

    const int tile = blockIdx.x, b = blockIdx.y, t = threadIdx.x;

    if (t < KC) NkU[t] = nkIn[b * KC + t];
    __syncthreads();
    for (int i = t; i < KC * LD; i += 256)
        muS[i >> 6][i & 63] = msIn[b * KC * LD + i] / NkU[i >> 6];
    __syncthreads();
    if (t < KC) {
        float s = 0.f;
        for (int l = 0; l < LD; l++) { const float m = muS[t][l]; s = fmaf(m, m, s); }
        float sn = 0.f;
        for (int k = 0; k < KC; k++) sn += NkU[k];
        m2lp[t] = -0.5f * s + logf(NkU[t] / sn);
    }
    __syncthreads();

    const int n = tile * 256 + t;
    const int sidx = n / MC, m = n % MC;
    const long bs = (long)b * SEQ + sidx;
    const float* zr = &z[((long)b * NPTS + n) * LD];

    float acc[KC];
#pragma unroll
    for (int k = 0; k < KC; k++) acc[k] = 0.f;
    float x2 = 0.f;
#pragma unroll
    for (int l4 = 0; l4 < 16; l4++) {
        const float4 zv = ((const float4*)zr)[l4];
        x2 = fmaf(zv.x, zv.x, fmaf(zv.y, zv.y, fmaf(zv.z, zv.z, fmaf(zv.w, zv.w, x2))));
#pragma unroll
        for (int k = 0; k < KC; k++) {
            const float4 mv = *(const float4*)&muS[k][l4 * 4];
            acc[k] = fmaf(zv.x, mv.x, acc[k]);
            acc[k] = fmaf(zv.y, mv.y, acc[k]);
            acc[k] = fmaf(zv.z, mv.z, acc[k]);
            acc[k] = fmaf(zv.w, mv.w, acc[k]);
        }
    }
    float mx = -1e30f;
    float llv[KC];
#pragma unroll
    for (int k = 0; k < KC; k++) { llv[k] = acc[k] + m2lp[k]; mx = fmaxf(mx, llv[k]); }
    float s = 0.f;
#pragma unroll
    for (int k = 0; k < KC; k++) s += expf(llv[k] - mx);
    const float log_pz = -0.5f * x2 + mx + logf(s) + LD * LOG_NORM;

    const float* lvr = &stats[bs * 128 + 64];
    const float* er = &eps[(bs * MC + m) * LD];
    float slv = 0.f, se2 = 0.f;
#pragma unroll
    for (int l4 = 0; l4 < 16; l4++) {
        const float4 lv = ((const float4*)lvr)[l4];
        slv += lv.x + lv.y + lv.z + lv.w;
        const float4 e = ((const float4*)er)[l4];
        se2 = fmaf(e.x, e.x, fmaf(e.y, e.y, fmaf(e.z, e.z, fmaf(e.w, e.w, se2))));
    }
    const float log_qz = -0.5f * (slv + se2) + LD * LOG_NORM;

    float v = log_qz - log_pz;
    v = warpReduceSum(v);
    if ((t & 63) == 0) redS[t >> 6] = v;
    __syncthreads();
    if (t == 0) {
        atomicAdd(&scal[1], redS[0] + redS[1] + redS[2] + redS[3]);
        __threadfence();
        const unsigned d = atomicAdd((unsigned*)&scal[2], 1u);
        if (d == 159u) {
            __threadfence();
            const float r0 = __hip_atomic_load(&scal[0], __ATOMIC_RELAXED,
                                               __HIP_MEMORY_SCOPE_AGENT);
            const float k1 = __hip_atomic_load(&scal[1], __ATOMIC_RELAXED,
                                               __HIP_MEMORY_SCOPE_AGENT);
            out[0] = r0 * (1.f / (float)NROWS);
            out[1] = k1 * (1.f / (float)NROWS);
        }
    }
}

// ---------------------------------------------------------------------------
extern "C" void kernel_launch(void* const* d_in, const int* in_sizes, int n_in,
                              void* d_out, int out_size, void* d_ws, size_t ws_size,
                              hipStream_t stream)
{
    const float* H   = (const float*)d_in[0];
    const float* eps = (const float*)d_in[1];
    const float* wq  = (const float*)d_in[2];
    const float* bq  = (const float*)d_in[3];
    const float* wk  = (const float*)d_in[4];
    const float* bk  = (const float*)d_in[5];
    const float* wv  = (const float*)d_in[6];
    const float* bv  = (const float*)d_in[7];
    const float* wo  = (const float*)d_in[8];
    const float* bo  = (const float*)d_in[9];
    const float* wz  = (const float*)d_in[10];
    const float* bz  = (const float*)d_in[11];
    const float* w1  = (const float*)d_in[12];
    const float* b1  = (const float*)d_in[13];
    const float* w2  = (const float*)d_in[14];
    const float* b2  = (const float*)d_in[15];
    const float* w3  = (const float*)d_in[16];
    const float* b3  = (const float*)d_in[17];
    const int* init_idx = (const int*)d_in[18];
    float* out = (float*)d_out;
    float* wsf = (float*)d_ws;

    // ---- workspace layout (float slots), ws = 256 MiB, used ~240 MB ----
    const long o_scal  = 0;
    const long o_nk    = 1024;
    const long o_ms    = 4096;
    const long o_st    = 131072;
    const long o_zb    = 655360;
    const long o_z16   = 3276800;
    const long o_q     = 4587520;
    const long o_k     = 6684672;
    const long o_vT    = 8781824;
    const long o_o     = 10878976;
    const long o_h1    = 12976128;
    const long o_qkvT0 = 15073280;
    const long o_woT0  = 15859712;
    const long o_qkvT1 = 16121856;
    const long o_woT1  = 16908288;
    const long o_wzT   = 17170432;
    const long o_w1T   = 17235968;
    const long o_w2T   = 17268736;
    const long o_w3T   = 17793024;
    const long o_d1    = 18055168;
    const long o_d2    = 39026688;   // ends 59998208 (240 MB)

    const long PL = (long)BS_TOT * DIM;
    bf* qh  = (bf*)(wsf + o_q);   bf* ql  = qh + PL;
    bf* kh  = (bf*)(wsf + o_k);   bf* kl_ = kh + PL;
    bf* vTh = (bf*)(wsf + o_vT);  bf* vTl = vTh + PL;
    bf* oh  = (bf*)(wsf + o_o);   bf* ol  = oh + PL;
    bf* h1h = (bf*)(wsf + o_h1);  bf* h1l = h1h + PL;
    bf* h2h = qh;                 bf* h2l = ql;
    bf* qkvTh0 = (bf*)(wsf + o_qkvT0); bf* qkvTl0 = qkvTh0 + 1536L * 512;
    bf* woTh0  = (bf*)(wsf + o_woT0);  bf* woTl0  = woTh0 + 512L * 512;
    bf* qkvTh1 = (bf*)(wsf + o_qkvT1); bf* qkvTl1 = qkvTh1 + 1536L * 512;
    bf* woTh1  = (bf*)(wsf + o_woT1);  bf* woTl1  = woTh1 + 512L * 512;
    bf* wzTh = (bf*)(wsf + o_wzT);     bf* wzTl = wzTh + 128L * 512;
    bf* w1T = (bf*)(wsf + o_w1T);
    bf* w2T = (bf*)(wsf + o_w2T);
    bf* w3T = (bf*)(wsf + o_w3T);
    bf* z16 = (bf*)(wsf + o_z16);
    bf* d1  = (bf*)(wsf + o_d1);
    bf* d2  = (bf*)(wsf + o_d2);
    float* st = wsf + o_st;
    float* zb = wsf + o_zb;
    float* scal = wsf + o_scal;
    float* msP = wsf + o_ms;
    float* nkP = wsf + o_nk;

    const dim3 blk(256);

    // ---- all conversions + scal zero + EM buffer zero, one launch ----
    conv_all<<<3077, blk, 0, stream>>>(
        H, h1h, h1l,
        wq, wk, wv, wo,
        qkvTh0, qkvTl0, woTh0, woTl0,
        qkvTh1, qkvTl1, woTh1, woTl1,
        wz, wzTh, wzTl, w1, w1T, w2, w2T, w3, w3T,
        scal, msP, nkP);

    // ---- 2x MAB on split-bf16 MFMA ----
    for (int i = 0; i < 2; i++) {
        const long boff = (long)i * DIM;
        bf* qkh = i ? qkvTh1 : qkvTh0;  bf* qkl = i ? qkvTl1 : qkvTl0;
        bf* wh  = i ? woTh1 : woTh0;    bf* wl  = i ? woTl1 : woTl0;

        gemm3t<0><<<dim3(12, 64), blk, 0, stream>>>(
            h1h, h1l, qkh, qkl, 512, 512, 512,
            bq + boff, bk + boff, bv + boff, nullptr,
            qh, ql, kh, kl_, vTh, vTl, nullptr, nullptr);
        attn_fused<<<dim3(4, 64), blk, 0, stream>>>(qh, ql, kh, kl_, vTh, vTl, oh, ol);
        bf* houth = (i == 0) ? h1h : h2h;
        bf* houtl = (i == 0) ? h1l : h2l;
        gemm3t<3><<<dim3(4, 64), blk, 0, stream>>>(
            oh, ol, wh, wl, 512, 512, 512,
            bo + boff, nullptr, nullptr, nullptr,
            houth, houtl, nullptr, nullptr, nullptr, nullptr, oh, ol);
    }

    // ---- stats = h2 @ wz + bz ----
    gemm3t<4><<<dim3(1, 64), blk, 0, stream>>>(
        h2h, h2l, wzTh, wzTl, 512, 512, 512,
        bz, nullptr, nullptr, st,
        nullptr, nullptr, nullptr, nullptr, nullptr, nullptr, nullptr, nullptr);

    // ---- z (fp32 exact + bf16 copy) ----
    zgen<<<2560, blk, 0, stream>>>(st, eps, zb, z16);

    // ---- decoder MLP + fused rec_loss, single dispatch per layer ----
    gemm_mfma<false><<<dim3(8, 320), blk, 0, stream>>>(
        z16, w1T, d1, b1, nullptr, nullptr, 64, 1024);
    gemm_mfma<false><<<dim3(8, 320), blk, 0, stream>>>(
        d1, w2T, d2, b2, nullptr, nullptr, 1024, 1024);
    gemm_mfma<true><<<dim3(4, 320), blk, 0, stream>>>(
        d2, w3T, nullptr, b3, H, scal + 0, 1024, 512);

    // ---- EM: em_step<FIRST> replaces em_init+step0, then 4 more, KL ----
    em_step<true><<<dim3(10, 16), blk, 0, stream>>>(
        zb, init_idx, nullptr, nullptr,
        msP + 1L * 16 * KC * LD, nkP + 1L * 16 * KC);
    for (int it = 1; it < 5; it++) {
        em_step<false><<<dim3(10, 16), blk, 0, stream>>>(
            zb, nullptr,
            msP + (long)it * 16 * KC * LD, nkP + (long)it * 16 * KC,
            msP + (long)(it + 1) * 16 * KC * LD, nkP + (long)(it + 1) * 16 * KC);
    }
    // KL + folded finalize (last block writes out)
    kl_kernel<<<dim3(10, 16), blk, 0, stream>>>(
        zb, st, eps,
        msP + 5L * 16 * KC * LD, nkP + 5L * 16 * KC, scal, out);
}

// Round 8
// 607.415 us; speedup vs baseline: 1.0430x; 1.0430x over previous
//
#include <hip/hip_runtime.h>
#include <hip/hip_bf16.h>
#include <math.h>

// ---------------------------------------------------------------------------
// GMVAE fused pipeline. Round 18 (fixing r17's attn regression):
//  - attn_fused: parallel P-slab write kept (r17, bit-exact verified), but V
//    staging is now a 4-deep prefetch issued BEFORE the P-write (latency
//    hides under P-write VALU work). PV phase: 3 barriers total instead of
//    16; V region double-pass (kc0-3, then kc4-7 into same 64KB region).
//    red/red2 moved above the P/V regions (no overlay hazard).
//    Same kc-ascending MFMA order, same slab mapping -> bit-exact.
//  - em_step keeps r17 vectorized staging.
// Everything else unchanged from r16/r17 (verified, absmax 0.0).
// ---------------------------------------------------------------------------

#define BATCH 16
#define SEQ 256
#define DIM 512
#define NH 4
#define DH 128
#define LD 64
#define KC 20
#define MC 10
#define NPTS 2560
#define BS_TOT 4096
#define NROWS 40960
#define LOG_NORM (-0.9189385332046727f)

typedef __attribute__((ext_vector_type(8))) short bf16x8;
typedef __attribute__((ext_vector_type(4))) float f32x4;
typedef __hip_bfloat16 bf;

__device__ inline float warpReduceSum(float v) {
    for (int o = 32; o > 0; o >>= 1) v += __shfl_down(v, o);
    return v;
}

__device__ inline void async_copy16(const bf* g, bf* l) {
    __builtin_amdgcn_global_load_lds(
        (const __attribute__((address_space(1))) unsigned int*)g,
        (__attribute__((address_space(3))) unsigned int*)l, 16, 0, 0);
}

__device__ inline void split_store(float x, bf* ph, bf* pl, long idx) {
    const bf h = __float2bfloat16(x);
    ph[idx] = h;
    pl[idx] = __float2bfloat16(x - __bfloat162float(h));
}

// ---------------------------------------------------------------------------
// Split-bf16 MFMA GEMM, 64x128 tile, BK=32 staged, K-unrolled x2 (two buffer
// sets, one barrier pair per 64-K). 4 waves x (4x2 MFMAs x 3 split groups)
// per 32-K tile. K must be a multiple of 64 (512 here).
// MODE: 0=QKV(fused q/k/vT out) 3=OPROJ(bias,relu,+resid) 4=STATS(fp32+bias)
// ---------------------------------------------------------------------------
template<int MODE>
__global__ __launch_bounds__(256, 3)
void gemm3t(const bf* __restrict__ Ah, const bf* __restrict__ Al,
            const bf* __restrict__ Bh, const bf* __restrict__ Bl,
            int K, int lda, int ldb,
            const float* __restrict__ b0, const float* __restrict__ b1v,
            const float* __restrict__ b2v,
            float* __restrict__ outF,
            bf* __restrict__ P1h, bf* __restrict__ P1l,
            bf* __restrict__ P2h, bf* __restrict__ P2l,
            bf* __restrict__ P3h, bf* __restrict__ P3l,
            const bf* __restrict__ Rh, const bf* __restrict__ Rl)
{
    // two 24 KB buffer sets
    __shared__ __align__(16) char smem[49152];
    float* Xs = (float*)smem;        // epilogue overlay [64][68] = 17408 B

    const int t = threadIdx.x;
    const int m0 = blockIdx.y * 64, n0 = blockIdx.x * 128;
    const int w = t >> 6, lane = t & 63;
    const int wn = w * 32;
    const int fm = lane & 15, quad = lane >> 4, fk = quad * 8;
    const int srow = t >> 2, scol = (t & 3) * 8;

    f32x4 acc[4][2];
#pragma unroll
    for (int i = 0; i < 4; i++)
#pragma unroll
        for (int j = 0; j < 2; j++) acc[i][j] = (f32x4){0.f, 0.f, 0.f, 0.f};

    const int nk2 = K >> 6;
    for (int kk2 = 0; kk2 < nk2; kk2++) {
#pragma unroll
        for (int h = 0; h < 2; h++) {
            const int kk = kk2 * 2 + h;
            char* base = smem + h * 24576;
            bf* Ash = (bf*)base;
            bf* Asl = (bf*)(base + 4096);
            bf* Bsh = (bf*)(base + 8192);
            bf* Bsl = (bf*)(base + 16384);
            const long ao = (long)(m0 + srow) * lda + kk * 32 + scol;
            const long bo = (long)(n0 + srow) * ldb + kk * 32 + scol;
            async_copy16(Ah + ao, Ash + w * 512);
            async_copy16(Al + ao, Asl + w * 512);
            async_copy16(Bh + bo, Bsh + w * 512);
            async_copy16(Bh + bo + 64L * ldb, Bsh + 2048 + w * 512);
            async_copy16(Bl + bo, Bsl + w * 512);
            async_copy16(Bl + bo + 64L * ldb, Bsl + 2048 + w * 512);
        }
        __syncthreads();

#pragma unroll
        for (int h = 0; h < 2; h++) {
            char* base = smem + h * 24576;
            bf* Ash = (bf*)base;
            bf* Asl = (bf*)(base + 4096);
            bf* Bsh = (bf*)(base + 8192);
            bf* Bsl = (bf*)(base + 16384);
            bf16x8 afh[4], afl[4], bfh[2], bfl[2];
#pragma unroll
            for (int mi = 0; mi < 4; mi++) {
                afh[mi] = *(const bf16x8*)&Ash[(mi * 16 + fm) * 32 + fk];
                afl[mi] = *(const bf16x8*)&Asl[(mi * 16 + fm) * 32 + fk];
            }
#pragma unroll
            for (int ni = 0; ni < 2; ni++) {
                bfh[ni] = *(const bf16x8*)&Bsh[(wn + ni * 16 + fm) * 32 + fk];
                bfl[ni] = *(const bf16x8*)&Bsl[(wn + ni * 16 + fm) * 32 + fk];
            }
#pragma unroll
            for (int mi = 0; mi < 4; mi++)
#pragma unroll
                for (int ni = 0; ni < 2; ni++) {
                    acc[mi][ni] = __builtin_amdgcn_mfma_f32_16x16x32_bf16(
                        afh[mi], bfh[ni], acc[mi][ni], 0, 0, 0);
                    acc[mi][ni] = __builtin_amdgcn_mfma_f32_16x16x32_bf16(
                        afh[mi], bfl[ni], acc[mi][ni], 0, 0, 0);
                    acc[mi][ni] = __builtin_amdgcn_mfma_f32_16x16x32_bf16(
                        afl[mi], bfh[ni], acc[mi][ni], 0, 0, 0);
                }
        }
        __syncthreads();
    }

    // ---- epilogue: two 64-col half-passes through LDS fp32 staging ----
    const int rl = t >> 2;
    const int cc4 = (t & 3) * 16;

    for (int p = 0; p < 2; p++) {
        if ((w >> 1) == p) {
            const int cb = wn - p * 64;
#pragma unroll
            for (int mi = 0; mi < 4; mi++)
#pragma unroll
                for (int ni = 0; ni < 2; ni++) {
                    const int c = cb + ni * 16 + fm;
#pragma unroll
                    for (int r = 0; r < 4; r++)
                        Xs[(mi * 16 + quad * 4 + r) * 68 + c] = acc[mi][ni][r];
                }
        }
        __syncthreads();

        if (MODE == 0 && n0 >= 1024) {
            const int hh = (n0 >> 7) & 3;
            const int dd = p * 64 + rl;
            const int bb = m0 >> 8;
            const int sb = (m0 & 255) + cc4;
            const float bias = b2v[hh * 128 + dd];
            const long ob = (((long)(bb * NH + hh) * DH + dd) << 8) + sb;
#pragma unroll
            for (int j = 0; j < 2; j++) {
                bf16x8 vh, vl;
#pragma unroll
                for (int i = 0; i < 8; i++) {
                    const float x = Xs[(cc4 + j * 8 + i) * 68 + rl] + bias;
                    const bf h = __float2bfloat16(x);
                    vh[i] = *(const short*)&h;
                    const bf l = __float2bfloat16(x - __bfloat162float(h));
                    vl[i] = *(const short*)&l;
                }
                *(bf16x8*)&P3h[ob + j * 8] = vh;
                *(bf16x8*)&P3l[ob + j * 8] = vl;
            }
        } else {
            float xv[16];
#pragma unroll
            for (int i = 0; i < 4; i++)
                *(float4*)&xv[i * 4] = *(const float4*)&Xs[rl * 68 + cc4 + i * 4];

            if (MODE == 0) {
                const int which = n0 >> 9;
                const int colq = (n0 & 511) + p * 64 + cc4;
                const float* bias = which ? b1v : b0;
                bf* Ph = which ? P2h : P1h;
                bf* Pl = which ? P2l : P1l;
                const long ob = (long)(m0 + rl) * 512 + colq;
#pragma unroll
                for (int j = 0; j < 2; j++) {
                    bf16x8 vh, vl;
#pragma unroll
                    for (int i = 0; i < 8; i++) {
                        const float x = xv[j * 8 + i] + bias[colq + j * 8 + i];
                        const bf h = __float2bfloat16(x); vh[i] = *(const short*)&h;
                        const bf l = __float2bfloat16(x - __bfloat162float(h));
                        vl[i] = *(const short*)&l;
                    }
                    *(bf16x8*)&Ph[ob + j * 8] = vh;
                    *(bf16x8*)&Pl[ob + j * 8] = vl;
                }
            } else if (MODE == 3) {
                const int colg = n0 + p * 64 + cc4;
                const long ob = (long)(m0 + rl) * 512 + colg;
#pragma unroll
                for (int j = 0; j < 2; j++) {
                    const bf16x8 rh = *(const bf16x8*)&Rh[ob + j * 8];
                    const bf16x8 rv = *(const bf16x8*)&Rl[ob + j * 8];
                    bf16x8 vh, vl;
#pragma unroll
                    for (int i = 0; i < 8; i++) {
                        short sh = rh[i], sl = rv[i];
                        float x = fmaxf(xv[j * 8 + i] + b0[colg + j * 8 + i], 0.f)
                                + __bfloat162float(*(const bf*)&sh)
                                + __bfloat162float(*(const bf*)&sl);
                        const bf h = __float2bfloat16(x); vh[i] = *(const short*)&h;
                        const bf l = __float2bfloat16(x - __bfloat162float(h));
                        vl[i] = *(const short*)&l;
                    }
                    *(bf16x8*)&P1h[ob + j * 8] = vh;
                    *(bf16x8*)&P1l[ob + j * 8] = vl;
                }
            } else {
                const int colg = p * 64 + cc4;
                const long ob = (long)(m0 + rl) * 128 + colg;
#pragma unroll
                for (int i = 0; i < 4; i++) {
                    float4 v = *(float4*)&xv[i * 4];
                    v.x += b0[colg + i * 4 + 0];
                    v.y += b0[colg + i * 4 + 1];
                    v.z += b0[colg + i * 4 + 2];
                    v.w += b0[colg + i * 4 + 3];
                    *(float4*)&outF[ob + i * 4] = v;
                }
            }
        }
        __syncthreads();
    }
}

// ---------------------------------------------------------------------------
// Fused attention, r18. QK^T + softmax unchanged (r16). PV phase:
//  - all 4 waves write their P slices into per-kc slabs (r17, bit-exact)
//  - V prefetched 4 kc deep, copies issued BEFORE the P-write so HBM/L2
//    latency hides under the P-write VALU work
//  - 3 barriers in the whole PV phase (was 16); kc-ascending MFMA order
//    and slab mapping unchanged -> bit-exact.
// LDS: P slabs 0..64K (overlay dead Q/K region), V region 64K..128K,
// red/red2 above at 128K..130K. 1 block/CU (grid 256 = 1/CU anyway).
// ---------------------------------------------------------------------------
__global__ __launch_bounds__(256)
void attn_fused(const bf* __restrict__ qh, const bf* __restrict__ ql,
                const bf* __restrict__ kh, const bf* __restrict__ kl,
                const bf* __restrict__ vTh, const bf* __restrict__ vTl,
                bf* __restrict__ oh, bf* __restrict__ ol)
{
    __shared__ __align__(16) char smem[133120];
    bf* Qsh = (bf*)smem;            bf* Qsl = (bf*)(smem + 4096);
    bf* Ksh = (bf*)(smem + 8192);   bf* Ksl = (bf*)(smem + 24576);
    bf* PhB = (bf*)smem;             // 8 slabs x [64][32] hi  (32 KB)
    bf* PlB = (bf*)(smem + 32768);   // 8 slabs x [64][32] lo  (32 KB)
    bf* VhR = (bf*)(smem + 65536);   // 4 slabs x [128][32] hi (32 KB)
    bf* VlR = (bf*)(smem + 98304);   // 4 slabs x [128][32] lo (32 KB)
    float (*red)[4]  = (float(*)[4])(smem + 131072);
    float (*red2)[4] = (float(*)[4])(smem + 132096);

    const int t = threadIdx.x;
    const int z = blockIdx.y;
    const int m0 = blockIdx.x * 64;
    const int bb = z >> 2, hh = z & 3;
    const long hOff = (long)bb * 131072 + (long)hh * 128;
    const long vOff = (long)z * 32768;

    const int w = t >> 6, lane = t & 63;
    const int fm = lane & 15;
    const int quad = lane >> 4;
    const int fk = quad * 8;
    const int srow = t >> 2, scol = (t & 3) * 8;

    f32x4 acc[4][4];
#pragma unroll
    for (int i = 0; i < 4; i++)
#pragma unroll
        for (int j = 0; j < 4; j++) acc[i][j] = (f32x4){0.f, 0.f, 0.f, 0.f};

    for (int kk = 0; kk < 4; kk++) {
        const long ao = hOff + (long)(m0 + srow) * 512 + kk * 32 + scol;
        const long bo = hOff + (long)srow * 512 + kk * 32 + scol;
        async_copy16(qh + ao, Qsh + w * 512);
        async_copy16(ql + ao, Qsl + w * 512);
#pragma unroll
        for (int j = 0; j < 4; j++) {
            async_copy16(kh + bo + (long)j * 64 * 512, Ksh + w * 512 + j * 2048);
            async_copy16(kl + bo + (long)j * 64 * 512, Ksl + w * 512 + j * 2048);
        }
        __syncthreads();

        bf16x8 afh[4], afl[4];
#pragma unroll
        for (int mi = 0; mi < 4; mi++) {
            afh[mi] = *(const bf16x8*)&Qsh[(mi * 16 + fm) * 32 + fk];
            afl[mi] = *(const bf16x8*)&Qsl[(mi * 16 + fm) * 32 + fk];
        }
#pragma unroll
        for (int ni = 0; ni < 4; ni++) {
            const bf16x8 bh = *(const bf16x8*)&Ksh[(w * 64 + ni * 16 + fm) * 32 + fk];
            const bf16x8 bl = *(const bf16x8*)&Ksl[(w * 64 + ni * 16 + fm) * 32 + fk];
#pragma unroll
            for (int mi = 0; mi < 4; mi++) {
                acc[mi][ni] = __builtin_amdgcn_mfma_f32_16x16x32_bf16(
                    afh[mi], bh, acc[mi][ni], 0, 0, 0);
                acc[mi][ni] = __builtin_amdgcn_mfma_f32_16x16x32_bf16(
                    afh[mi], bl, acc[mi][ni], 0, 0, 0);
                acc[mi][ni] = __builtin_amdgcn_mfma_f32_16x16x32_bf16(
                    afl[mi], bh, acc[mi][ni], 0, 0, 0);
            }
        }
        __syncthreads();
    }

    const float alpha = 0.044194173824159216f;
#pragma unroll
    for (int mi = 0; mi < 4; mi++)
#pragma unroll
        for (int r = 0; r < 4; r++) {
            float m = -1e30f;
#pragma unroll
            for (int ni = 0; ni < 4; ni++) m = fmaxf(m, acc[mi][ni][r]);
            for (int o = 8; o > 0; o >>= 1) m = fmaxf(m, __shfl_xor(m, o));
            if (fm == 0) red[mi * 16 + quad * 4 + r][w] = m;
        }
    __syncthreads();
    float invr[4][4];
#pragma unroll
    for (int mi = 0; mi < 4; mi++)
#pragma unroll
        for (int r = 0; r < 4; r++) {
            const int rowl = mi * 16 + quad * 4 + r;
            const float mx = fmaxf(fmaxf(red[rowl][0], red[rowl][1]),
                                   fmaxf(red[rowl][2], red[rowl][3]));
            float s = 0.f;
#pragma unroll
            for (int ni = 0; ni < 4; ni++) {
                const float e = __expf((acc[mi][ni][r] - mx) * alpha);
                acc[mi][ni][r] = e;
                s += e;
            }
            for (int o = 8; o > 0; o >>= 1) s += __shfl_xor(s, o);
            if (fm == 0) red2[rowl][w] = s;
        }
    __syncthreads();
#pragma unroll
    for (int mi = 0; mi < 4; mi++)
#pragma unroll
        for (int r = 0; r < 4; r++) {
            const int rowl = mi * 16 + quad * 4 + r;
            invr[mi][r] = 1.f / (red2[rowl][0] + red2[rowl][1] + red2[rowl][2] + red2[rowl][3]);
        }

    // ---- issue V prefetch for kc 0..3 (latency hides under P-write) ----
#pragma unroll
    for (int kc = 0; kc < 4; kc++) {
        const long vo = vOff + (long)srow * 256 + kc * 32 + scol;
        async_copy16(vTh + vo, VhR + kc * 4096 + w * 512);
        async_copy16(vTh + vo + 64L * 256, VhR + kc * 4096 + 2048 + w * 512);
        async_copy16(vTl + vo, VlR + kc * 4096 + w * 512);
        async_copy16(vTl + vo + 64L * 256, VlR + kc * 4096 + 2048 + w * 512);
    }

    // ---- all waves write their P slices (slabs 2w, 2w+1; overlays Q/K) ----
#pragma unroll
    for (int half = 0; half < 2; half++) {
        bf* Ph = PhB + (2 * w + half) * 2048;
        bf* Pl = PlB + (2 * w + half) * 2048;
        const int nib = half * 2;
#pragma unroll
        for (int mi = 0; mi < 4; mi++)
#pragma unroll
            for (int r = 0; r < 4; r++) {
                const int row = mi * 16 + quad * 4 + r;
#pragma unroll
                for (int j = 0; j < 2; j++) {
                    const float p = acc[mi][nib + j][r] * invr[mi][r];
                    const int cc = j * 16 + fm;
                    const bf h = __float2bfloat16(p);
                    Ph[row * 32 + cc] = h;
                    Pl[row * 32 + cc] = __float2bfloat16(p - __bfloat162float(h));
                }
            }
    }

    __syncthreads();                 // P slabs + V(0..3) ready

    f32x4 acc2[4][2];
#pragma unroll
    for (int i = 0; i < 4; i++)
#pragma unroll
        for (int j = 0; j < 2; j++) acc2[i][j] = (f32x4){0.f, 0.f, 0.f, 0.f};

#pragma unroll
    for (int kc = 0; kc < 4; kc++) {
        const bf* Psh_k = PhB + kc * 2048;
        const bf* Psl_k = PlB + kc * 2048;
        const bf* Vh_k = VhR + kc * 4096;
        const bf* Vl_k = VlR + kc * 4096;
        bf16x8 pfh[4], pfl[4];
#pragma unroll
        for (int mi = 0; mi < 4; mi++) {
            pfh[mi] = *(const bf16x8*)&Psh_k[(mi * 16 + fm) * 32 + fk];
            pfl[mi] = *(const bf16x8*)&Psl_k[(mi * 16 + fm) * 32 + fk];
        }
#pragma unroll
        for (int ni = 0; ni < 2; ni++) {
            const bf16x8 vh = *(const bf16x8*)&Vh_k[(w * 32 + ni * 16 + fm) * 32 + fk];
            const bf16x8 vl = *(const bf16x8*)&Vl_k[(w * 32 + ni * 16 + fm) * 32 + fk];
#pragma unroll
            for (int mi = 0; mi < 4; mi++) {
                acc2[mi][ni] = __builtin_amdgcn_mfma_f32_16x16x32_bf16(
                    pfh[mi], vh, acc2[mi][ni], 0, 0, 0);
                acc2[mi][ni] = __builtin_amdgcn_mfma_f32_16x16x32_bf16(
                    pfh[mi], vl, acc2[mi][ni], 0, 0, 0);
                acc2[mi][ni] = __builtin_amdgcn_mfma_f32_16x16x32_bf16(
                    pfl[mi], vh, acc2[mi][ni], 0, 0, 0);
            }
        }
    }

    __syncthreads();                 // all waves done reading V region

#pragma unroll
    for (int kc = 4; kc < 8; kc++) {
        const long vo = vOff + (long)srow * 256 + kc * 32 + scol;
        async_copy16(vTh + vo, VhR + (kc - 4) * 4096 + w * 512);
        async_copy16(vTh + vo + 64L * 256, VhR + (kc - 4) * 4096 + 2048 + w * 512);
        async_copy16(vTl + vo, VlR + (kc - 4) * 4096 + w * 512);
        async_copy16(vTl + vo + 64L * 256, VlR + (kc - 4) * 4096 + 2048 + w * 512);
    }
    __syncthreads();                 // V(4..7) ready

#pragma unroll
    for (int kc = 4; kc < 8; kc++) {
        const bf* Psh_k = PhB + kc * 2048;
        const bf* Psl_k = PlB + kc * 2048;
        const bf* Vh_k = VhR + (kc - 4) * 4096;
        const bf* Vl_k = VlR + (kc - 4) * 4096;
        bf16x8 pfh[4], pfl[4];
#pragma unroll
        for (int mi = 0; mi < 4; mi++) {
            pfh[mi] = *(const bf16x8*)&Psh_k[(mi * 16 + fm) * 32 + fk];
            pfl[mi] = *(const bf16x8*)&Psl_k[(mi * 16 + fm) * 32 + fk];
        }
#pragma unroll
        for (int ni = 0; ni < 2; ni++) {
            const bf16x8 vh = *(const bf16x8*)&Vh_k[(w * 32 + ni * 16 + fm) * 32 + fk];
            const bf16x8 vl = *(const bf16x8*)&Vl_k[(w * 32 + ni * 16 + fm) * 32 + fk];
#pragma unroll
            for (int mi = 0; mi < 4; mi++) {
                acc2[mi][ni] = __builtin_amdgcn_mfma_f32_16x16x32_bf16(
                    pfh[mi], vh, acc2[mi][ni], 0, 0, 0);
                acc2[mi][ni] = __builtin_amdgcn_mfma_f32_16x16x32_bf16(
                    pfh[mi], vl, acc2[mi][ni], 0, 0, 0);
                acc2[mi][ni] = __builtin_amdgcn_mfma_f32_16x16x32_bf16(
                    pfl[mi], vh, acc2[mi][ni], 0, 0, 0);
            }
        }
    }

#pragma unroll
    for (int ni = 0; ni < 2; ni++) {
        const int col = hh * 128 + w * 32 + ni * 16 + fm;
#pragma unroll
        for (int mi = 0; mi < 4; mi++)
#pragma unroll
            for (int r = 0; r < 4; r++) {
                const int row = mi * 16 + quad * 4 + r;
                const long idx = (long)(bb * 256 + m0 + row) * 512 + col;
                const float x = acc2[mi][ni][r]
                    + __bfloat162float(qh[idx]) + __bfloat162float(ql[idx]);
                split_store(x, oh, ol, idx);
            }
    }
}

// ---------------------------------------------------------------------------
// plain-bf16 decoder GEMM, single dispatch, XCD swizzle, K-unrolled x2.
// ---------------------------------------------------------------------------
template<bool SQLOSS>
__global__ __launch_bounds__(256, 4)
void gemm_mfma(const bf* __restrict__ A, const bf* __restrict__ BT,
               bf* __restrict__ C,
               const float* __restrict__ bias,
               const float* __restrict__ Href,
               float* __restrict__ lossAcc,
               int K, int N)
{
    // two 16 KB buffer sets (A+B each 8 KB)
    __shared__ __align__(16) char smem[32768];
    bf* Cs  = (bf*)smem;             // epilogue overlay [64][136] = 17408 B
    __shared__ float redS[4];

    const int t = threadIdx.x;
    const int flat = blockIdx.y * gridDim.x + blockIdx.x;
    const int lane8 = flat & 7;
    const int grp = flat >> 3;
    const int n_blk = grp % gridDim.x;
    const int m_blk = (grp / gridDim.x) * 8 + lane8;
    const int m0 = m_blk * 128, n0 = n_blk * 128;

    const int w = t >> 6, lane = t & 63;
    const int wm = (w >> 1) * 64, wn = (w & 1) * 64;
    const int fm = lane & 15;
    const int quad = lane >> 4;
    const int fk = quad * 8;
    const int srow = t >> 2, scol = (t & 3) * 8;

    f32x4 acc[4][4];
#pragma unroll
    for (int i = 0; i < 4; i++)
#pragma unroll
        for (int j = 0; j < 4; j++) acc[i][j] = (f32x4){0.f, 0.f, 0.f, 0.f};

    const int nk2 = K >> 6;
    for (int kt2 = 0; kt2 < nk2; kt2++) {
#pragma unroll
        for (int h = 0; h < 2; h++) {
            const int kt = kt2 * 2 + h;
            bf* Asg = (bf*)(smem + h * 16384);
            bf* Bsg = (bf*)(smem + h * 16384 + 8192);
            const bf* ga = A + (long)(m0 + srow) * K + kt * 32 + scol;
            const bf* gb = BT + (long)(n0 + srow) * K + kt * 32 + scol;
            async_copy16(ga, Asg + w * 512);
            async_copy16(ga + 64L * K, Asg + 2048 + w * 512);
            async_copy16(gb, Bsg + w * 512);
            async_copy16(gb + 64L * K, Bsg + 2048 + w * 512);
        }
        __syncthreads();

#pragma unroll
        for (int h = 0; h < 2; h++) {
            bf* Asg = (bf*)(smem + h * 16384);
            bf* Bsg = (bf*)(smem + h * 16384 + 8192);
            bf16x8 af[4], bfr[4];
#pragma unroll
            for (int mi = 0; mi < 4; mi++)
                af[mi] = *(const bf16x8*)&Asg[(wm + mi * 16 + fm) * 32 + fk];
#pragma unroll
            for (int ni = 0; ni < 4; ni++)
                bfr[ni] = *(const bf16x8*)&Bsg[(wn + ni * 16 + fm) * 32 + fk];
#pragma unroll
            for (int mi = 0; mi < 4; mi++)
#pragma unroll
                for (int ni = 0; ni < 4; ni++)
                    acc[mi][ni] = __builtin_amdgcn_mfma_f32_16x16x32_bf16(
                        af[mi], bfr[ni], acc[mi][ni], 0, 0, 0);
        }
        __syncthreads();
    }

    if (SQLOSS) {
        float lsum = 0.f;
#pragma unroll
        for (int ni = 0; ni < 4; ni++) {
            const int col = n0 + wn + ni * 16 + fm;
            const float b = bias[col];
#pragma unroll
            for (int mi = 0; mi < 4; mi++)
#pragma unroll
                for (int r = 0; r < 4; r++) {
                    const int row = m0 + wm + mi * 16 + quad * 4 + r;
                    const float x = fmaxf(acc[mi][ni][r] + b, 0.f);
                    const float d = x - Href[(long)(row / MC) * DIM + col];
                    lsum = fmaf(d, d, lsum);
                }
        }
        lsum = warpReduceSum(lsum);
        if (lane == 0) redS[w] = lsum;
        __syncthreads();
        if (t == 0) atomicAdd(lossAcc, redS[0] + redS[1] + redS[2] + redS[3]);
    } else {
        for (int hf = 0; hf < 2; hf++) {
            if ((w >> 1) == hf) {
#pragma unroll
                for (int ni = 0; ni < 4; ni++) {
                    const int c = wn + ni * 16 + fm;
                    const float bv = bias[n0 + c];
#pragma unroll
                    for (int mi = 0; mi < 4; mi++)
#pragma unroll
                        for (int r = 0; r < 4; r++) {
                            const float x = fmaxf(acc[mi][ni][r] + bv, 0.f);
                            Cs[(mi * 16 + quad * 4 + r) * 136 + c] = __float2bfloat16(x);
                        }
                }
            }
            __syncthreads();
            const int rl2 = t >> 2, cc2 = (t & 3) * 32;
            const long ob = (long)(m0 + hf * 64 + rl2) * N + n0 + cc2;
#pragma unroll
            for (int j = 0; j < 4; j++)
                *(bf16x8*)&C[ob + j * 8] = *(const bf16x8*)&Cs[rl2 * 136 + cc2 + j * 8];
            __syncthreads();
        }
    }
}

// ---------------------------------------------------------------------------
// conv_all (r16 verified): block-range dispatch, 64x64 LDS tile-transposes.
// ---------------------------------------------------------------------------
__global__ __launch_bounds__(256)
void conv_all(
    const float* __restrict__ H, bf* __restrict__ h0h, bf* __restrict__ h0l,
    const float* __restrict__ wq, const float* __restrict__ wk,
    const float* __restrict__ wv, const float* __restrict__ wo,
    bf* __restrict__ qkvTh0, bf* __restrict__ qkvTl0,
    bf* __restrict__ woTh0, bf* __restrict__ woTl0,
    bf* __restrict__ qkvTh1, bf* __restrict__ qkvTl1,
    bf* __restrict__ woTh1, bf* __restrict__ woTl1,
    const float* __restrict__ wz, bf* __restrict__ wzTh, bf* __restrict__ wzTl,
    const float* __restrict__ w1, bf* __restrict__ w1T,
    const float* __restrict__ w2, bf* __restrict__ w2T,
    const float* __restrict__ w3, bf* __restrict__ w3T,
    float* __restrict__ scal, float* __restrict__ msP, float* __restrict__ nkP)
{
    __shared__ float tS[64][65];
    const int b = blockIdx.x, t = threadIdx.x;

    if (b < 2048) {                  // ---- H split, float4 ----
        const long base = ((long)b << 10) + (t << 2);
        const float4 v = *(const float4*)&H[base];
        ushort4 uh, ul;
        {
            const bf h0 = __float2bfloat16(v.x);
            uh.x = *(const unsigned short*)&h0;
            const bf l0 = __float2bfloat16(v.x - __bfloat162float(h0));
            ul.x = *(const unsigned short*)&l0;
        }
        {
            const bf h0 = __float2bfloat16(v.y);
            uh.y = *(const unsigned short*)&h0;
            const bf l0 = __float2bfloat16(v.y - __bfloat162float(h0));
            ul.y = *(const unsigned short*)&l0;
        }
        {
            const bf h0 = __float2bfloat16(v.z);
            uh.z = *(const unsigned short*)&h0;
            const bf l0 = __float2bfloat16(v.z - __bfloat162float(h0));
            ul.z = *(const unsigned short*)&l0;
        }
        {
            const bf h0 = __float2bfloat16(v.w);
            uh.w = *(const unsigned short*)&h0;
            const bf l0 = __float2bfloat16(v.w - __bfloat162float(h0));
            ul.w = *(const unsigned short*)&l0;
        }
        *(ushort4*)&h0h[base] = uh;
        *(ushort4*)&h0l[base] = ul;
        return;
    }
    const int bb = b - 2048;

    if (bb >= 928) {
        if (bb < 1028) {             // ---- zero msP buffers 1..5 ----
            const long j = ((long)(bb - 928) << 10) + (t << 2);
            *(float4*)&msP[20480 + j] = (float4){0.f, 0.f, 0.f, 0.f};
        } else {                     // ---- zero nkP 1..5 + scal ----
            for (int i = t; i < 1600; i += 256) nkP[320 + i] = 0.f;
            if (t < 16) scal[t] = 0.f;
        }
        return;
    }

    // ---- tile-transpose sections ----
    const float* src; bf* dH; bf* dL = nullptr;
    int Ncols, ldT, k0, n0; long dofs = 0; bool split;

    if (bb < 512) {                  // MAB weights
        const int m = bb >> 6, tile = bb & 63;
        const int layer = m >> 2, seg = m & 3;
        k0 = (tile >> 3) * 64; n0 = (tile & 7) * 64;
        src = ((seg == 0) ? wq : (seg == 1) ? wk : (seg == 2) ? wv : wo)
              + (long)layer * 262144;
        Ncols = 512; ldT = 512; split = true;
        if (seg < 3) {
            dH = layer ? qkvTh1 : qkvTh0;
            dL = layer ? qkvTl1 : qkvTl0;
            dofs = (long)seg * 262144;
        } else {
            dH = layer ? woTh1 : woTh0;
            dL = layer ? woTl1 : woTl0;
        }
    } else if (bb < 528) {           // wz
        const int i = bb - 512;
        k0 = (i >> 1) * 64; n0 = (i & 1) * 64;
        src = wz; Ncols = 128; ldT = 512; split = true;
        dH = wzTh; dL = wzTl;
    } else if (bb < 544) {           // w1
        const int i = bb - 528;
        k0 = 0; n0 = i * 64;
        src = w1; Ncols = 1024; ldT = 64; split = false;
        dH = w1T;
    } else if (bb < 800) {           // w2
        const int i = bb - 544;
        k0 = (i >> 4) * 64; n0 = (i & 15) * 64;
        src = w2; Ncols = 1024; ldT = 1024; split = false;
        dH = w2T;
    } else {                         // w3
        const int i = bb - 800;
        k0 = (i >> 3) * 64; n0 = (i & 7) * 64;
        src = w3; Ncols = 512; ldT = 1024; split = false;
        dH = w3T;
    }

    // load 64x64 fp32 tile coalesced
    {
        const int r = t >> 2, cq = (t & 3) * 16;
#pragma unroll
        for (int i = 0; i < 4; i++) {
            const float4 v = *(const float4*)&src[(long)(k0 + r) * Ncols + n0 + cq + i * 4];
            tS[r][cq + i * 4 + 0] = v.x;
            tS[r][cq + i * 4 + 1] = v.y;
            tS[r][cq + i * 4 + 2] = v.z;
            tS[r][cq + i * 4 + 3] = v.w;
        }
    }
    __syncthreads();

    // write transposed, coalesced bf16x8
    {
        const int nn = t >> 2, kq = (t & 3) * 16;
        const long ob = dofs + (long)(n0 + nn) * ldT + k0 + kq;
#pragma unroll
        for (int j2 = 0; j2 < 2; j2++) {
            bf16x8 vh, vl;
#pragma unroll
            for (int j = 0; j < 8; j++) {
                const float x = tS[kq + j2 * 8 + j][nn];
                const bf h = __float2bfloat16(x);
                vh[j] = *(const short*)&h;
                const bf l = __float2bfloat16(x - __bfloat162float(h));
                vl[j] = *(const short*)&l;
            }
            *(bf16x8*)&dH[ob + j2 * 8] = vh;
            if (split) *(bf16x8*)&dL[ob + j2 * 8] = vl;
        }
    }
}

// ---------------------------------------------------------------------------
__global__ __launch_bounds__(256)
void zgen(const float* __restrict__ stats, const float* __restrict__ eps,
          float* __restrict__ z, bf* __restrict__ z16)
{
    const int idx = blockIdx.x * 256 + threadIdx.x;
    const int bs = idx / 160;
    const int r = idx % 160;
    const int l4 = r % 16;
    const float4 e = ((const float4*)eps)[idx];
    const float4 mn = ((const float4*)stats)[bs * 32 + l4];
    const float4 lv = ((const float4*)stats)[bs * 32 + 16 + l4];
    float4 zz;
    zz.x = fmaf(e.x, expf(0.5f * lv.x), mn.x);
    zz.y = fmaf(e.y, expf(0.5f * lv.y), mn.y);
    zz.z = fmaf(e.z, expf(0.5f * lv.z), mn.z);
    zz.w = fmaf(e.w, expf(0.5f * lv.w), mn.w);
    ((float4*)z)[idx] = zz;
    bf* zp = z16 + (long)idx * 4;
    zp[0] = __float2bfloat16(zz.x);
    zp[1] = __float2bfloat16(zz.y);
    zp[2] = __float2bfloat16(zz.z);
    zp[3] = __float2bfloat16(zz.w);
}

// ---------------------------------------------------------------------------
// EM step (r15 verified + r17 vectorized staging): zbS LDS z-tile (float4
// coalesced copy, bit-exact), muS[KC][68] float4, FIRST folds init.
// ---------------------------------------------------------------------------
template<bool FIRST>
__global__ __launch_bounds__(256)
void em_step(const float* __restrict__ z, const int* __restrict__ init_idx,
             const float* __restrict__ msIn, const float* __restrict__ nkIn,
             float* __restrict__ msOut, float* __restrict__ nkOut)
{
    __shared__ float muS[KC][68];
    __shared__ float m2lp[KC];
    __shared__ float NkU[KC];
    __shared__ float postS[KC][256];
    __shared__ float NkS[KC];
    __shared__ float zbS[256][64];   // 64 KB tile stage

    const int tile = blockIdx.x, b = blockIdx.y, t = threadIdx.x;
    const int lane = t & 63, w = t >> 6;

    const float* zbg = &z[((long)b * NPTS + (long)tile * 256) * LD];

    // stage z tile -> LDS, float4 coalesced (bit-exact copy)
    {
        const int c4 = (t & 15) * 4;
        const int r0 = t >> 4;
#pragma unroll
        for (int p = 0; p < 16; p++) {
            const int r = r0 + p * 16;
            *(float4*)&zbS[r][c4] = *(const float4*)&zbg[(long)r * 64 + c4];
        }
    }

    if (t < KC) NkU[t] = FIRST ? 1.f : nkIn[b * KC + t];
    __syncthreads();
    if (FIRST) {
        for (int i = t; i < KC * LD; i += 256) {
            const int k = i >> 6, l = i & 63;
            muS[k][l] = z[((long)b * NPTS + init_idx[b * KC + k]) * LD + l];
        }
    } else {
        for (int i = t; i < KC * LD; i += 256)
            muS[i >> 6][i & 63] = msIn[b * KC * LD + i] / NkU[i >> 6];
    }
    __syncthreads();
    if (t < KC) {
        float s = 0.f;
        for (int l = 0; l < LD; l++) { const float m = muS[t][l]; s = fmaf(m, m, s); }
        float sn = 0.f;
        for (int k = 0; k < KC; k++) sn += NkU[k];
        m2lp[t] = -0.5f * s + logf(NkU[t] / sn);
    }
    __syncthreads();

    // ---- E-step (muS via aligned float4; same fmaf order) ----
    const float* zr = &zbg[(long)t * LD];
    float acc[KC];
#pragma unroll
    for (int k = 0; k < KC; k++) acc[k] = 0.f;
#pragma unroll
    for (int l4 = 0; l4 < 16; l4++) {
        const float4 zv = ((const float4*)zr)[l4];
#pragma unroll
        for (int k = 0; k < KC; k++) {
            const float4 mv = *(const float4*)&muS[k][l4 * 4];
            acc[k] = fmaf(zv.x, mv.x, acc[k]);
            acc[k] = fmaf(zv.y, mv.y, acc[k]);
            acc[k] = fmaf(zv.z, mv.z, acc[k]);
            acc[k] = fmaf(zv.w, mv.w, acc[k]);
        }
    }
    float mx = -1e30f;
    float llv[KC];
#pragma unroll
    for (int k = 0; k < KC; k++) { llv[k] = acc[k] + m2lp[k]; mx = fmaxf(mx, llv[k]); }
    float s = 0.f;
#pragma unroll
    for (int k = 0; k < KC; k++) { llv[k] = expf(llv[k] - mx); s += llv[k]; }
    const float inv = 1.f / s;
#pragma unroll
    for (int k = 0; k < KC; k++) postS[k][t] = llv[k] * inv;
    __syncthreads();

#pragma unroll
    for (int kk = 0; kk < 5; kk++) {
        const int k = w * 5 + kk;
        float p = postS[k][lane] + postS[k][lane + 64] + postS[k][lane + 128] + postS[k][lane + 192];
        p = warpReduceSum(p);
        if (lane == 0) NkS[k] = p;
    }
    __syncthreads();

    // ---- M-step: chains fed from zbS (same values, same n2 order) ----
#pragma unroll
    for (int j = 0; j < 5; j++) {
        const int o = t + j * 256;
        const int k = o >> 6, l = o & 63;
        float sacc = 0.f;
        for (int n2 = 0; n2 < 256; n2++)
            sacc = fmaf(postS[k][n2], zbS[n2][l], sacc);
        atomicAdd(&msOut[b * KC * LD + o], sacc);
    }
    if (t < KC) atomicAdd(&nkOut[b * KC + t], NkS[t]);
}

// ---------------------------------------------------------------------------
// KL kernel + folded finalize (r16 verified).
// ---------------------------------------------------------------------------
__global__ __launch_bounds__(256)
void kl_kernel(const float* __restrict__ z, const float* __restrict__ stats,
               const float* __restrict__ eps,
               const float* __restrict__ msIn, const float* __restrict__ nkIn,
               float* __restrict__ scal, float* __restrict__ out)
{
    __shared__ float muS[KC][68];
    __shared__ float m2lp[KC];
    __shared__ float NkU[KC];
    __shared__ float redS[4];

    const int tile = blockIdx.x, b = blockIdx.y, t = threadIdx.x;

    if (t < KC) NkU[t] = nkIn[b * KC + t];
    __syncthreads();
    for (int i = t; i < KC * LD; i += 256)
        muS[i >> 6][i & 63] = msIn[b * KC * LD + i] / NkU[i >> 6];
    __syncthreads();
    if (t < KC) {
        float s = 0.f;
        for (int l = 0; l < LD; l++) { const float m = muS[t][l]; s = fmaf(m, m, s); }
        float sn = 0.f;
        for (int k = 0; k < KC; k++) sn += NkU[k];
        m2lp[t] = -0.5f * s + logf(NkU[t] / sn);
    }
    __syncthreads();

    const int n = tile * 256 + t;
    const int sidx = n / MC, m = n % MC;
    const long bs = (long)b * SEQ + sidx;
    const float* zr = &z[((long)b * NPTS + n) * LD];

    float acc[KC];
#pragma unroll
    for (int k = 0; k < KC; k++) acc[k] = 0.f;
    float x2 = 0.f;
#pragma unroll
    for (int l4 = 0; l4 < 16; l4++) {
        const float4 zv = ((const float4*)zr)[l4];
        x2 = fmaf(zv.x, zv.x, fmaf(zv.y, zv.y, fmaf(zv.z, zv.z, fmaf(zv.w, zv.w, x2))));
#pragma unroll
        for (int k = 0; k < KC; k++) {
            const float4 mv = *(const float4*)&muS[k][l4 * 4];
            acc[k] = fmaf(zv.x, mv.x, acc[k]);
            acc[k] = fmaf(zv.y, mv.y, acc[k]);
            acc[k] = fmaf(zv.z, mv.z, acc[k]);
            acc[k] = fmaf(zv.w, mv.w, acc[k]);
        }
    }
    float mx = -1e30f;
    float llv[KC];
#pragma unroll
    for (int k = 0; k < KC; k++) { llv[k] = acc[k] + m2lp[k]; mx = fmaxf(mx, llv[k]); }
    float s = 0.f;
#pragma unroll
    for (int k = 0; k < KC; k++) s += expf(llv[k] - mx);
    const float log_pz = -0.5f * x2 + mx + logf(s) + LD * LOG_NORM;

    const float* lvr = &stats[bs * 128 + 64];
    const float* er = &eps[(bs * MC + m) * LD];
    float slv = 0.f, se2 = 0.f;
#pragma unroll
    for (int l4 = 0; l4 < 16; l4++) {
        const float4 lv = ((const float4*)lvr)[l4];
        slv += lv.x + lv.y + lv.z + lv.w;
        const float4 e = ((const float4*)er)[l4];
        se2 = fmaf(e.x, e.x, fmaf(e.y, e.y, fmaf(e.z, e.z, fmaf(e.w, e.w, se2))));
    }
    const float log_qz = -0.5f * (slv + se2) + LD * LOG_NORM;

    float v = log_qz - log_pz;
    v = warpReduceSum(v);
    if ((t & 63) == 0) redS[t >> 6] = v;
    __syncthreads();
    if (t == 0) {
        atomicAdd(&scal[1], redS[0] + redS[1] + redS[2] + redS[3]);
        __threadfence();
        const unsigned d = atomicAdd((unsigned*)&scal[2], 1u);
        if (d == 159u) {
            __threadfence();
            const float r0 = __hip_atomic_load(&scal[0], __ATOMIC_RELAXED,
                                               __HIP_MEMORY_SCOPE_AGENT);
            const float k1 = __hip_atomic_load(&scal[1], __ATOMIC_RELAXED,
                                               __HIP_MEMORY_SCOPE_AGENT);
            out[0] = r0 * (1.f / (float)NROWS);
            out[1] = k1 * (1.f / (float)NROWS);
        }
    }
}

// ---------------------------------------------------------------------------
extern "C" void kernel_launch(void* const* d_in, const int* in_sizes, int n_in,
                              void* d_out, int out_size, void* d_ws, size_t ws_size,
                              hipStream_t stream)
{
    const float* H   = (const float*)d_in[0];
    const float* eps = (const float*)d_in[1];
    const float* wq  = (const float*)d_in[2];
    const float* bq  = (const float*)d_in[3];
    const float* wk  = (const float*)d_in[4];
    const float* bk  = (const float*)d_in[5];
    const float* wv  = (const float*)d_in[6];
    const float* bv  = (const float*)d_in[7];
    const float* wo  = (const float*)d_in[8];
    const float* bo  = (const float*)d_in[9];
    const float* wz  = (const float*)d_in[10];
    const float* bz  = (const float*)d_in[11];
    const float* w1  = (const float*)d_in[12];
    const float* b1  = (const float*)d_in[13];
    const float* w2  = (const float*)d_in[14];
    const float* b2  = (const float*)d_in[15];
    const float* w3  = (const float*)d_in[16];
    const float* b3  = (const float*)d_in[17];
    const int* init_idx = (const int*)d_in[18];
    float* out = (float*)d_out;
    float* wsf = (float*)d_ws;

    // ---- workspace layout (float slots), ws = 256 MiB, used ~240 MB ----
    const long o_scal  = 0;
    const long o_nk    = 1024;
    const long o_ms    = 4096;
    const long o_st    = 131072;
    const long o_zb    = 655360;
    const long o_z16   = 3276800;
    const long o_q     = 4587520;
    const long o_k     = 6684672;
    const long o_vT    = 8781824;
    const long o_o     = 10878976;
    const long o_h1    = 12976128;
    const long o_qkvT0 = 15073280;
    const long o_woT0  = 15859712;
    const long o_qkvT1 = 16121856;
    const long o_woT1  = 16908288;
    const long o_wzT   = 17170432;
    const long o_w1T   = 17235968;
    const long o_w2T   = 17268736;
    const long o_w3T   = 17793024;
    const long o_d1    = 18055168;
    const long o_d2    = 39026688;   // ends 59998208 (240 MB)

    const long PL = (long)BS_TOT * DIM;
    bf* qh  = (bf*)(wsf + o_q);   bf* ql  = qh + PL;
    bf* kh  = (bf*)(wsf + o_k);   bf* kl_ = kh + PL;
    bf* vTh = (bf*)(wsf + o_vT);  bf* vTl = vTh + PL;
    bf* oh  = (bf*)(wsf + o_o);   bf* ol  = oh + PL;
    bf* h1h = (bf*)(wsf + o_h1);  bf* h1l = h1h + PL;
    bf* h2h = qh;                 bf* h2l = ql;
    bf* qkvTh0 = (bf*)(wsf + o_qkvT0); bf* qkvTl0 = qkvTh0 + 1536L * 512;
    bf* woTh0  = (bf*)(wsf + o_woT0);  bf* woTl0  = woTh0 + 512L * 512;
    bf* qkvTh1 = (bf*)(wsf + o_qkvT1); bf* qkvTl1 = qkvTh1 + 1536L * 512;
    bf* woTh1  = (bf*)(wsf + o_woT1);  bf* woTl1  = woTh1 + 512L * 512;
    bf* wzTh = (bf*)(wsf + o_wzT);     bf* wzTl = wzTh + 128L * 512;
    bf* w1T = (bf*)(wsf + o_w1T);
    bf* w2T = (bf*)(wsf + o_w2T);
    bf* w3T = (bf*)(wsf + o_w3T);
    bf* z16 = (bf*)(wsf + o_z16);
    bf* d1  = (bf*)(wsf + o_d1);
    bf* d2  = (bf*)(wsf + o_d2);
    float* st = wsf + o_st;
    float* zb = wsf + o_zb;
    float* scal = wsf + o_scal;
    float* msP = wsf + o_ms;
    float* nkP = wsf + o_nk;

    const dim3 blk(256);

    // ---- all conversions + scal zero + EM buffer zero, one launch ----
    conv_all<<<3077, blk, 0, stream>>>(
        H, h1h, h1l,
        wq, wk, wv, wo,
        qkvTh0, qkvTl0, woTh0, woTl0,
        qkvTh1, qkvTl1, woTh1, woTl1,
        wz, wzTh, wzTl, w1, w1T, w2, w2T, w3, w3T,
        scal, msP, nkP);

    // ---- 2x MAB on split-bf16 MFMA ----
    for (int i = 0; i < 2; i++) {
        const long boff = (long)i * DIM;
        bf* qkh = i ? qkvTh1 : qkvTh0;  bf* qkl = i ? qkvTl1 : qkvTl0;
        bf* wh  = i ? woTh1 : woTh0;    bf* wl  = i ? woTl1 : woTl0;

        gemm3t<0><<<dim3(12, 64), blk, 0, stream>>>(
            h1h, h1l, qkh, qkl, 512, 512, 512,
            bq + boff, bk + boff, bv + boff, nullptr,
            qh, ql, kh, kl_, vTh, vTl, nullptr, nullptr);
        attn_fused<<<dim3(4, 64), blk, 0, stream>>>(qh, ql, kh, kl_, vTh, vTl, oh, ol);
        bf* houth = (i == 0) ? h1h : h2h;
        bf* houtl = (i == 0) ? h1l : h2l;
        gemm3t<3><<<dim3(4, 64), blk, 0, stream>>>(
            oh, ol, wh, wl, 512, 512, 512,
            bo + boff, nullptr, nullptr, nullptr,
            houth, houtl, nullptr, nullptr, nullptr, nullptr, oh, ol);
    }

    // ---- stats = h2 @ wz + bz ----
    gemm3t<4><<<dim3(1, 64), blk, 0, stream>>>(
        h2h, h2l, wzTh, wzTl, 512, 512, 512,
        bz, nullptr, nullptr, st,
        nullptr, nullptr, nullptr, nullptr, nullptr, nullptr, nullptr, nullptr);

    // ---- z (fp32 exact + bf16 copy) ----
    zgen<<<2560, blk, 0, stream>>>(st, eps, zb, z16);

    // ---- decoder MLP + fused rec_loss, single dispatch per layer ----
    gemm_mfma<false><<<dim3(8, 320), blk, 0, stream>>>(
        z16, w1T, d1, b1, nullptr, nullptr, 64, 1024);
    gemm_mfma<false><<<dim3(8, 320), blk, 0, stream>>>(
        d1, w2T, d2, b2, nullptr, nullptr, 1024, 1024);
    gemm_mfma<true><<<dim3(4, 320), blk, 0, stream>>>(
        d2, w3T, nullptr, b3, H, scal + 0, 1024, 512);

    // ---- EM: em_step<FIRST> replaces em_init+step0, then 4 more, KL ----
    em_step<true><<<dim3(10, 16), blk, 0, stream>>>(
        zb, init_idx, nullptr, nullptr,
        msP + 1L * 16 * KC * LD, nkP + 1L * 16 * KC);
    for (int it = 1; it < 5; it++) {
        em_step<false><<<dim3(10, 16), blk, 0, stream>>>(
            zb, nullptr,
            msP + (long)it * 16 * KC * LD, nkP + (long)it * 16 * KC,
            msP + (long)(it + 1) * 16 * KC * LD, nkP + (long)(it + 1) * 16 * KC);
    }
    // KL + folded finalize (last block writes out)
    kl_kernel<<<dim3(10, 16), blk, 0, stream>>>(
        zb, st, eps,
        msP + 5L * 16 * KC * LD, nkP + 5L * 16 * KC, scal, out);
}